// Round 3
// baseline (79.501 us; speedup 1.0000x reference)
//
#include <hip/hip_runtime.h>

#define DM 2048
#define DS 16
#define BATCH 2
#define SEQ 4096
#define P (BATCH * DM)  // 4096 independent scans
#define TT 16           // time-tile staged through LDS

// ws layout (floats):
//   [0,      S)   Abar  [DS][DM]
//   [S,     2S)   Bbar  [DS][DM]
//   [2S,    3S)   PowL  [DS][DM]   (Abar^L)
//   [3S,    4S)   Ct    [DS][DM]
//   [4S, ......)  Hloc  [NC][DS][P]

__global__ __launch_bounds__(256) void k_params(const float* __restrict__ A_log,
                                                const float* __restrict__ B,
                                                const float* __restrict__ C,
                                                const float* __restrict__ delta,
                                                float* __restrict__ ws, int Lsteps) {
  int j = blockIdx.x * 256 + threadIdx.x;
  if (j >= DM * DS) return;
  int n = j / DM, d = j - n * DM;
  float dl = delta[d];
  float a = -expf(A_log[d * DS + n]);
  ws[j] = expf(dl * a);                               // Abar
  ws[DS * DM + j] = dl * B[d * DS + n];               // Bbar
  ws[2 * DS * DM + j] = expf(dl * a * (float)Lsteps); // Abar^L
  ws[3 * DS * DM + j] = C[d * DS + n];                // Ct
}

// ---- cooperative x-tile staging helpers ----
// Block covers 256 consecutive p (one chunk k). Tile = TT time-steps x 256 ch.
// Cooperative load: thread loads 4 float4s (rows lrow+4j, col lcol), perfectly
// contiguous 16B per lane -> global_load_dwordx4 streams.

__global__ __launch_bounds__(256) void k_local(const float* __restrict__ x,
                                               const float* __restrict__ ws,
                                               float* __restrict__ Hloc, int Lsteps) {
  __shared__ float xs[2][TT][256];
  int bid = blockIdx.x;
  int k = bid >> 4;            // 16 blocks per chunk
  int p0 = (bid & 15) << 8;
  int tid = threadIdx.x;
  int p = p0 + tid;
  int d = p & (DM - 1);
  int b = p >> 11;

  const float* Abar = ws;
  const float* Bbar = ws + DS * DM;
  float ab[DS], bb[DS], h[DS];
#pragma unroll
  for (int n = 0; n < DS; n++) {
    ab[n] = Abar[n * DM + d];
    bb[n] = Bbar[n * DM + d];
    h[n] = 0.f;
  }

  const float* xbase = x + ((size_t)b * SEQ + (size_t)k * Lsteps) * DM + (p0 & (DM - 1));
  int lrow = tid >> 6;   // 0..3
  int lcol = tid & 63;   // float4 column

  int ntiles = Lsteps / TT;
  // preload tile 0
  {
    float4 r[4];
#pragma unroll
    for (int j = 0; j < 4; j++)
      r[j] = *(const float4*)(xbase + (size_t)(lrow + 4 * j) * DM + 4 * lcol);
#pragma unroll
    for (int j = 0; j < 4; j++)
      ((float4*)xs[0][lrow + 4 * j])[lcol] = r[j];
  }
  __syncthreads();

  for (int tile = 0; tile < ntiles; tile++) {
    int buf = tile & 1;
    float4 r[4];
    bool more = (tile + 1) < ntiles;
    if (more) {
      const float* nb = xbase + (size_t)(tile + 1) * TT * DM;
#pragma unroll
      for (int j = 0; j < 4; j++)
        r[j] = *(const float4*)(nb + (size_t)(lrow + 4 * j) * DM + 4 * lcol);
    }
#pragma unroll
    for (int t = 0; t < TT; t++) {
      float xv = xs[buf][t][tid];
#pragma unroll
      for (int n = 0; n < DS; n++) h[n] = fmaf(ab[n], h[n], bb[n] * xv);
    }
    if (more) {
#pragma unroll
      for (int j = 0; j < 4; j++)
        ((float4*)xs[buf ^ 1][lrow + 4 * j])[lcol] = r[j];
    }
    __syncthreads();
  }

  float* Hp = Hloc + (size_t)(k * DS) * P + p;
#pragma unroll
  for (int n = 0; n < DS; n++) Hp[n * P] = h[n];
}

// Phase 2: serial prefix over chunks, parallel over (n, p) = 65536 threads.
__global__ __launch_bounds__(256) void k_scan(float* __restrict__ Hloc,
                                              const float* __restrict__ ws, int nc) {
  int tid = blockIdx.x * 256 + threadIdx.x;  // DS*P threads
  int p = tid & (P - 1);
  int n = tid >> 12;
  int d = p & (DM - 1);
  const float* PowL = ws + 2 * DS * DM;
  float pw = PowL[n * DM + d];
  float carry = 0.f;
  float* Hp = Hloc + (size_t)n * P + p;
  const size_t stride = (size_t)DS * P;
  for (int k0 = 0; k0 < nc; k0 += 16) {
    float v[16];
#pragma unroll
    for (int j = 0; j < 16; j++) v[j] = Hp[(size_t)(k0 + j) * stride];
#pragma unroll
    for (int j = 0; j < 16; j++) {
      Hp[(size_t)(k0 + j) * stride] = carry;
      carry = fmaf(pw, carry, v[j]);
    }
  }
}

// Phase 3: rescan each chunk from its true start state; emit y.
__global__ __launch_bounds__(256) void k_final(const float* __restrict__ x,
                                               const float* __restrict__ ws,
                                               const float* __restrict__ Hloc,
                                               const float* __restrict__ Dp,
                                               float* __restrict__ out, int Lsteps) {
  __shared__ float xs[2][TT][256];
  int bid = blockIdx.x;
  int k = bid >> 4;
  int p0 = (bid & 15) << 8;
  int tid = threadIdx.x;
  int p = p0 + tid;
  int d = p & (DM - 1);
  int b = p >> 11;

  const float* Abar = ws;
  const float* Bbar = ws + DS * DM;
  const float* Ct = ws + 3 * DS * DM;
  float ab[DS], bb[DS], cc[DS], h[DS];
#pragma unroll
  for (int n = 0; n < DS; n++) {
    ab[n] = Abar[n * DM + d];
    bb[n] = Bbar[n * DM + d];
    cc[n] = Ct[n * DM + d];
  }
  const float* Hp = Hloc + (size_t)(k * DS) * P + p;
#pragma unroll
  for (int n = 0; n < DS; n++) h[n] = Hp[n * P];
  float Dd = Dp[d];

  size_t off = ((size_t)b * SEQ + (size_t)k * Lsteps) * DM;
  const float* xbase = x + off + (p0 & (DM - 1));
  float* ybase = out + off + d;
  int lrow = tid >> 6;
  int lcol = tid & 63;

  int ntiles = Lsteps / TT;
  {
    float4 r[4];
#pragma unroll
    for (int j = 0; j < 4; j++)
      r[j] = *(const float4*)(xbase + (size_t)(lrow + 4 * j) * DM + 4 * lcol);
#pragma unroll
    for (int j = 0; j < 4; j++)
      ((float4*)xs[0][lrow + 4 * j])[lcol] = r[j];
  }
  __syncthreads();

  for (int tile = 0; tile < ntiles; tile++) {
    int buf = tile & 1;
    float4 r[4];
    bool more = (tile + 1) < ntiles;
    if (more) {
      const float* nb = xbase + (size_t)(tile + 1) * TT * DM;
#pragma unroll
      for (int j = 0; j < 4; j++)
        r[j] = *(const float4*)(nb + (size_t)(lrow + 4 * j) * DM + 4 * lcol);
    }
    float* yp = ybase + (size_t)tile * TT * DM;
#pragma unroll
    for (int t = 0; t < TT; t++) {
      float xv = xs[buf][t][tid];
#pragma unroll
      for (int n = 0; n < DS; n++) h[n] = fmaf(ab[n], h[n], bb[n] * xv);
      float acc = Dd * xv;
#pragma unroll
      for (int n = 0; n < DS; n++) acc = fmaf(cc[n], h[n], acc);
      yp[(size_t)t * DM] = acc;
    }
    if (more) {
#pragma unroll
      for (int j = 0; j < 4; j++)
        ((float4*)xs[buf ^ 1][lrow + 4 * j])[lcol] = r[j];
    }
    __syncthreads();
  }
}

extern "C" void kernel_launch(void* const* d_in, const int* in_sizes, int n_in,
                              void* d_out, int out_size, void* d_ws, size_t ws_size,
                              hipStream_t stream) {
  const float* x = (const float*)d_in[0];
  const float* A_log = (const float*)d_in[1];
  const float* B = (const float*)d_in[2];
  const float* C = (const float*)d_in[3];
  const float* Dp = (const float*)d_in[4];
  const float* delta = (const float*)d_in[5];
  float* out = (float*)d_out;
  float* ws = (float*)d_ws;

  size_t base = 4 * (size_t)DS * DM;
  int nc = 64;
  while (nc > 16 && (base + (size_t)nc * DS * P) * 4 > ws_size) nc >>= 1;
  int Lsteps = SEQ / nc;
  float* Hloc = ws + base;

  k_params<<<(DM * DS + 255) / 256, 256, 0, stream>>>(A_log, B, C, delta, ws, Lsteps);
  k_local<<<nc * 16, 256, 0, stream>>>(x, ws, Hloc, Lsteps);
  k_scan<<<(DS * P) / 256, 256, 0, stream>>>(Hloc, ws, nc);
  k_final<<<nc * 16, 256, 0, stream>>>(x, ws, Hloc, Dp, out, Lsteps);
}

// Round 4
// 53.246 us; speedup vs baseline: 1.4931x; 1.4931x over previous
//
#include <hip/hip_runtime.h>

#define DM 2048
#define DS 16
#define BATCH 2
#define SEQ 4096
#define P (BATCH * DM)  // 4096 independent scans
#define UNR 8

// Rescaled state: g = h / B_bar  =>  g' = Abar*g + x  (one FMA/state).
// y = C.h + D*x = sum_n (C*delta*B)[n]*g[n] + D*x.
//
// ws layout (floats), S = DS*DM:
//   [0,   S)  Abar [DS][DM]   exp(delta*A)
//   [S,  2S)  CB   [DS][DM]   C * delta * B
//   [2S, 3S)  PowL [DS][DM]   Abar^Lsteps
//   [3S, ..)  Hloc [nc][DS][P]  (g-space chunk states)

__global__ __launch_bounds__(256) void k_params(const float* __restrict__ A_log,
                                                const float* __restrict__ B,
                                                const float* __restrict__ C,
                                                const float* __restrict__ delta,
                                                float* __restrict__ ws, int Lsteps) {
  int j = blockIdx.x * 256 + threadIdx.x;
  if (j >= DM * DS) return;
  int n = j / DM, d = j - n * DM;
  float dl = delta[d];
  float a = -expf(A_log[d * DS + n]);
  ws[j] = expf(dl * a);                                   // Abar
  ws[DS * DM + j] = C[d * DS + n] * dl * B[d * DS + n];   // CB
  ws[2 * DS * DM + j] = expf(dl * a * (float)Lsteps);     // Abar^L
}

// Phase 1: per-chunk local scan from g=0; store g at chunk end.
__global__ __launch_bounds__(256) void k_local(const float* __restrict__ x,
                                               const float* __restrict__ ws,
                                               float* __restrict__ Hloc, int Lsteps) {
  int tid = blockIdx.x * 256 + threadIdx.x;
  int p = tid & (P - 1);
  int k = tid >> 12;            // P = 4096
  int b = p >> 11;              // DM = 2048
  int d = p & (DM - 1);
  const float* Abar = ws;
  float ab[DS], g[DS];
#pragma unroll
  for (int n = 0; n < DS; n++) {
    ab[n] = Abar[n * DM + d];
    g[n] = 0.f;
  }
  const float* xp = x + ((size_t)b * SEQ + (size_t)k * Lsteps) * DM + d;
  for (int t = 0; t < Lsteps; t += UNR) {
    float xv[UNR];
#pragma unroll
    for (int j = 0; j < UNR; j++) xv[j] = xp[(size_t)j * DM];
#pragma unroll
    for (int j = 0; j < UNR; j++) {
#pragma unroll
      for (int n = 0; n < DS; n++) g[n] = fmaf(ab[n], g[n], xv[j]);
    }
    xp += (size_t)UNR * DM;
  }
  float* Hp = Hloc + (size_t)(k * DS) * P + p;
#pragma unroll
  for (int n = 0; n < DS; n++) Hp[n * P] = g[n];
}

// Phase 2: serial exclusive prefix over chunks, parallel over (n,p).
__global__ __launch_bounds__(256) void k_scan(float* __restrict__ Hloc,
                                              const float* __restrict__ ws, int nc) {
  int tid = blockIdx.x * 256 + threadIdx.x;  // DS*P threads
  int p = tid & (P - 1);
  int n = tid >> 12;
  int d = p & (DM - 1);
  const float* PowL = ws + 2 * DS * DM;
  float pw = PowL[n * DM + d];
  float carry = 0.f;
  float* Hp = Hloc + (size_t)n * P + p;
  const size_t stride = (size_t)DS * P;
  for (int k0 = 0; k0 < nc; k0 += 16) {
    float v[16];
#pragma unroll
    for (int j = 0; j < 16; j++) v[j] = Hp[(size_t)(k0 + j) * stride];
#pragma unroll
    for (int j = 0; j < 16; j++) {
      Hp[(size_t)(k0 + j) * stride] = carry;
      carry = fmaf(pw, carry, v[j]);
    }
  }
}

// Phase 3: rescan each chunk from its true start state; emit y.
__global__ __launch_bounds__(256) void k_final(const float* __restrict__ x,
                                               const float* __restrict__ ws,
                                               const float* __restrict__ Hloc,
                                               const float* __restrict__ Dp,
                                               float* __restrict__ out, int Lsteps) {
  int tid = blockIdx.x * 256 + threadIdx.x;
  int p = tid & (P - 1);
  int k = tid >> 12;
  int b = p >> 11;
  int d = p & (DM - 1);
  const float* Abar = ws;
  const float* CB = ws + DS * DM;
  float ab[DS], cb[DS], g[DS];
#pragma unroll
  for (int n = 0; n < DS; n++) {
    ab[n] = Abar[n * DM + d];
    cb[n] = CB[n * DM + d];
  }
  const float* Hp = Hloc + (size_t)(k * DS) * P + p;
#pragma unroll
  for (int n = 0; n < DS; n++) g[n] = Hp[n * P];
  float Dd = Dp[d];
  size_t off = ((size_t)b * SEQ + (size_t)k * Lsteps) * DM + d;
  const float* xp = x + off;
  float* yp = out + off;
  for (int t = 0; t < Lsteps; t += UNR) {
    float xv[UNR];
#pragma unroll
    for (int j = 0; j < UNR; j++) xv[j] = xp[(size_t)j * DM];
#pragma unroll
    for (int j = 0; j < UNR; j++) {
#pragma unroll
      for (int n = 0; n < DS; n++) g[n] = fmaf(ab[n], g[n], xv[j]);
      float acc = Dd * xv[j];
#pragma unroll
      for (int n = 0; n < DS; n++) acc = fmaf(cb[n], g[n], acc);
      yp[(size_t)j * DM] = acc;
    }
    xp += (size_t)UNR * DM;
    yp += (size_t)UNR * DM;
  }
}

extern "C" void kernel_launch(void* const* d_in, const int* in_sizes, int n_in,
                              void* d_out, int out_size, void* d_ws, size_t ws_size,
                              hipStream_t stream) {
  const float* x = (const float*)d_in[0];
  const float* A_log = (const float*)d_in[1];
  const float* B = (const float*)d_in[2];
  const float* C = (const float*)d_in[3];
  const float* Dp = (const float*)d_in[4];
  const float* delta = (const float*)d_in[5];
  float* out = (float*)d_out;
  float* ws = (float*)d_ws;

  size_t base = 3 * (size_t)DS * DM;
  int nc = 32;
  while (nc > 16 && (base + (size_t)nc * DS * P) * 4 > ws_size) nc >>= 1;
  int Lsteps = SEQ / nc;
  float* Hloc = ws + base;

  k_params<<<(DM * DS + 255) / 256, 256, 0, stream>>>(A_log, B, C, delta, ws, Lsteps);
  k_local<<<(nc * P) / 256, 256, 0, stream>>>(x, ws, Hloc, Lsteps);
  k_scan<<<(DS * P) / 256, 256, 0, stream>>>(Hloc, ws, nc);
  k_final<<<(nc * P) / 256, 256, 0, stream>>>(x, ws, Hloc, Dp, out, Lsteps);
}